// Round 12
// baseline (442.257 us; speedup 1.0000x reference)
//
#include <hip/hip_runtime.h>

// Problem constants: B=8, H=8, L=1024, DK=64
constexpr int SL = 1024;   // sequence length
constexpr int NBH = 64;    // B*H rows

// Workspace layout (float offsets)
constexpr int QP_OFF = 0;         // Qp [64][1024]
constexpr int KP_OFF = 65536;     // Kp [64][1024]
constexpr int Y_OFF  = 131072;    // conv outputs, 4 branches x [64][1024]
constexpr int QM_OFF = 655360;    // Qm [64][1024]
constexpr int KM_OFF = 720896;    // Km [64][1024]
constexpr int ST_OFF = 786432;    // BN stats [4][8][2] = 64 floats (atomic accum)
constexpr int C_OFF  = 786496;    // scalar c = dot(wbq,wbk)/8
constexpr int VT_OFF = 786560;    // V packed bf16 B-fragments: 4.19M ushort = 8.4 MB

typedef __attribute__((ext_vector_type(8))) short short8;
typedef __attribute__((ext_vector_type(4))) float f32x4;

__device__ inline unsigned short f2bf(float x) {
    unsigned int u = __float_as_uint(x);
    unsigned int r = (u + 0x7fff + ((u >> 16) & 1)) >> 16;  // RNE
    return (unsigned short)r;
}

// ---------------- K1: proj (Qp,Kp) + c + V bf16 B-fragment pack, fused ----
__global__ __launch_bounds__(256) void k_projpack(
    const float* __restrict__ Q, const float* __restrict__ K,
    const float* __restrict__ V,
    const float* __restrict__ wq, const float* __restrict__ wk,
    const float* __restrict__ wbq, const float* __restrict__ wbk,
    float* __restrict__ ws)
{
    int b = blockIdx.x;
    int tid = threadIdx.x;
    if (b < 8192) {
        bool isQ = b < 4096;
        const float* src = isQ ? Q : K;
        const float* w   = isQ ? wq : wk;
        int row = (b - (isQ ? 0 : 4096)) * 16 + (tid >> 4);
        int l16 = tid & 15;
        float4 x  = ((const float4*)(src + row * 64))[l16];
        float4 w4 = ((const float4*)w)[l16];
        float v = x.x * w4.x + x.y * w4.y + x.z * w4.z + x.w * w4.w;
        #pragma unroll
        for (int m = 8; m; m >>= 1) v += __shfl_xor(v, m);
        if (l16 == 0) ws[(isQ ? QP_OFF : KP_OFF) + row] = v;
    } else if (b < 10240) {
        // V pack: [bh][chunk4][dsub4][kstep8][lane64][j8]
        int t = (b - 8192) * 256 + tid;    // 524288 total
        int lane = t & 63;
        int s    = (t >> 6) & 7;
        int dsub = (t >> 9) & 3;
        int chunk= (t >> 11) & 3;
        int bh   = t >> 13;
        const float* vb = V + bh * (SL * 64);
        int k0 = chunk * 256 + s * 32 + (lane >> 4) * 8;
        int d  = dsub * 16 + (lane & 15);
        unsigned short o[8];
        #pragma unroll
        for (int j = 0; j < 8; j++) o[j] = f2bf(vb[(k0 + j) * 64 + d]);
        unsigned short* vt = (unsigned short*)(ws + VT_OFF);
        *(short8*)(vt + (size_t)t * 8) = *(short8*)o;
    } else {
        if (tid < 64) {
            ws[ST_OFF + tid] = 0.f;        // zero BN-stat accumulators
            float v = wbq[tid] * wbk[tid];
            #pragma unroll
            for (int m = 32; m; m >>= 1) v += __shfl_xor(v, m);
            if (tid == 0) ws[C_OFF] = v * 0.125f;  // / sqrt(64)
        }
    }
}

// ---------------- K2: conv1d + bias, accumulate BN stats ----------------
__global__ __launch_bounds__(256) void k_conv(
    float* __restrict__ ws,
    const float* __restrict__ w0, const float* __restrict__ b0,
    const float* __restrict__ w1, const float* __restrict__ b1,
    const float* __restrict__ w2, const float* __restrict__ b2,
    const float* __restrict__ w3, const float* __restrict__ b3)
{
    int branch = blockIdx.x >> 6;
    int n = (blockIdx.x >> 3) & 7;
    int seg = blockIdx.x & 7;
    int t0 = seg * 128;
    const float* wp = branch == 0 ? w0 : branch == 1 ? w1 : branch == 2 ? w2 : w3;
    const float* bp = branch == 0 ? b0 : branch == 1 ? b1 : branch == 2 ? b2 : b3;
    const int F = (branch & 1) ? 9 : 3;
    const int PAD = F >> 1;
    const float* x = ws + ((branch < 2) ? QP_OFF : KP_OFF) + n * 8 * SL;

    __shared__ float xl[8][136];    // 128 + halo 4 each side (offset +4)
    __shared__ float wl[8 * 8 * 9];
    __shared__ float bl[8];
    int tid = threadIdx.x;
    for (int i = tid; i < 8 * 8 * F; i += 256) wl[i] = wp[i];
    if (tid < 8) bl[tid] = bp[tid];
    for (int i = tid; i < 8 * 136; i += 256) {
        int ci = i / 136; int tt = i - ci * 136;
        int ta = t0 + tt - 4;
        xl[ci][tt] = (ta >= 0 && ta < SL) ? x[ci * SL + ta] : 0.f;
    }
    __syncthreads();
    int c = tid >> 5, u = tid & 31;
    float s1 = 0.f, s2 = 0.f;
    float* yout = ws + Y_OFF + branch * (NBH * SL) + (n * 8 + c) * SL + t0;
    #pragma unroll
    for (int q = 0; q < 4; q++) {
        int tl = q * 32 + u;
        float acc = bl[c];
        for (int ci = 0; ci < 8; ci++) {
            const float* xr = &xl[ci][tl + 4 - PAD];
            const float* wr = &wl[(c * 8 + ci) * F];
            for (int f = 0; f < F; f++) acc += wr[f] * xr[f];
        }
        yout[tl] = acc;
        s1 += acc; s2 += acc * acc;
    }
    #pragma unroll
    for (int m = 16; m; m >>= 1) {
        s1 += __shfl_xor(s1, m);
        s2 += __shfl_xor(s2, m);
    }
    if (u == 0) {
        atomicAdd(&ws[ST_OFF + (branch * 8 + c) * 2],     s1);
        atomicAdd(&ws[ST_OFF + (branch * 8 + c) * 2 + 1], s2);
    }
}

// ---------------- K3: fused BN(train) + softmax + concat-scramble max ------
__global__ __launch_bounds__(256) void k_bnmix(
    float* __restrict__ ws,
    const float* __restrict__ g0, const float* __restrict__ be0,
    const float* __restrict__ g1, const float* __restrict__ be1,
    const float* __restrict__ g2, const float* __restrict__ be2,
    const float* __restrict__ g3, const float* __restrict__ be3)
{
    int blk = blockIdx.x;
    int which = blk >> 6;
    int i = (blk >> 3) & 7, j = blk & 7;
    int n = 2 * i + (j >= 4 ? 1 : 0);
    int br = which * 2 + (n >= 8 ? 1 : 0);
    int row = n & 7;
    int tid = threadIdx.x;
    int half = tid >> 7;               // 0 -> channel c0, 1 -> c0+1
    int u = tid & 127;
    int c = 2 * (j & 3) + half;
    const float* gp = br == 0 ? g0 : br == 1 ? g1 : br == 2 ? g2 : g3;
    const float* bp = br == 0 ? be0 : br == 1 ? be1 : br == 2 ? be2 : be3;
    float s1 = ws[ST_OFF + (br * 8 + c) * 2];
    float s2 = ws[ST_OFF + (br * 8 + c) * 2 + 1];
    float mu  = s1 * (1.f / 8192.f);
    float var = s2 * (1.f / 8192.f) - mu * mu;   // biased var over (B, L)
    float sc = gp[c] * rsqrtf(var + 1e-5f);
    float sh = bp[c] - mu * sc;
    const float* y = ws + Y_OFF + br * (NBH * SL) + (row * 8 + c) * SL;
    float4 ya = ((const float4*)y)[u * 2];
    float4 yb = ((const float4*)y)[u * 2 + 1];
    float z[8] = { ya.x * sc + sh, ya.y * sc + sh, ya.z * sc + sh, ya.w * sc + sh,
                   yb.x * sc + sh, yb.y * sc + sh, yb.z * sc + sh, yb.w * sc + sh };
    float mx = z[0];
    #pragma unroll
    for (int q = 1; q < 8; q++) mx = fmaxf(mx, z[q]);
    __shared__ float r1[4], r2[4];
    #pragma unroll
    for (int m = 32; m; m >>= 1) mx = fmaxf(mx, __shfl_xor(mx, m));
    if ((tid & 63) == 0) r1[tid >> 6] = mx;
    __syncthreads();
    mx = half ? fmaxf(r1[2], r1[3]) : fmaxf(r1[0], r1[1]);
    float e[8];
    float s = 0.f;
    #pragma unroll
    for (int q = 0; q < 8; q++) { e[q] = __expf(z[q] - mx); s += e[q]; }
    #pragma unroll
    for (int m = 32; m; m >>= 1) s += __shfl_xor(s, m);
    if ((tid & 63) == 0) r2[tid >> 6] = s;
    __syncthreads();
    s = half ? (r2[2] + r2[3]) : (r2[0] + r2[1]);
    float inv = 1.f / s;
    float4 o = make_float4(fmaxf(e[0], e[1]) * inv, fmaxf(e[2], e[3]) * inv,
                           fmaxf(e[4], e[5]) * inv, fmaxf(e[6], e[7]) * inv);
    float* outp = ws + (which ? KM_OFF : QM_OFF) + i * 8192 + j * 1024 + half * 512;
    ((float4*)outp)[u] = o;
}

// ---------------- K4: fused rank-1 attn softmax + attn write + MFMA PV ----
// v9: EXACT r9 structure (banked 393.8) with ONE change: attn stores are
// NON-TEMPORAL (global_store nt, L2-bypass). The attn output is terminal
// (never re-read). Surviving theory after 5 falsifications: the 268 MB
// write flood transits L2 and evicts the VT table (FETCH ~220 MB invariant
// across occupancy/traffic/layout variants). NT stores remove the pollution
// AND any allocate-fetch: VT (8.4 MB) stays L2-resident for all 32 sharing
// blocks. Clean A/B vs r9: everything else byte-identical.
__global__ __launch_bounds__(256, 4) void k_attn(
    float* __restrict__ out, const float* __restrict__ ws)
{
    int p = blockIdx.x;
    int xcd = p & 7, idx = p >> 3;            // idx in 0..255
    int bh = xcd + 8 * (idx >> 5);
    int qt2 = idx & 31;                        // 32-row chunk (2 tiles of 16)
    int tid = threadIdx.x;

    __shared__ __align__(16) float kml[1024];
    __shared__ float rmx[4], rmn[4];
    __shared__ float wsum0[4][16], wsum1[4][16];
    __shared__ float accred[4][16][64];        // 16 KB, reused per tile

    const float* km = ws + KM_OFF + bh * SL;
    const float* qm = ws + QM_OFF + bh * SL + qt2 * 32;
    float c = ws[C_OFF];

    // stage Km; block max/min (logits monotone in Km -> exact max subtraction)
    float lmax = -1e30f, lmin = 1e30f;
    #pragma unroll
    for (int i = 0; i < 4; i++) {
        float v = km[tid + 256 * i];
        kml[tid + 256 * i] = v;
        lmax = fmaxf(lmax, v); lmin = fminf(lmin, v);
    }
    #pragma unroll
    for (int m = 32; m; m >>= 1) {
        lmax = fmaxf(lmax, __shfl_xor(lmax, m));
        lmin = fminf(lmin, __shfl_xor(lmin, m));
    }
    if ((tid & 63) == 0) { rmx[tid >> 6] = lmax; rmn[tid >> 6] = lmin; }
    __syncthreads();

    int w = tid >> 6, lane = tid & 63;
    int m16 = lane & 15, kg = lane >> 4;
    float kmax = fmaxf(fmaxf(rmx[0], rmx[1]), fmaxf(rmx[2], rmx[3]));
    float kmin = fminf(fminf(rmn[0], rmn[1]), fminf(rmn[2], rmn[3]));
    float a0 = c * qm[m16];                    // tile 0 (rows 0..15)
    float a1 = c * qm[16 + m16];               // tile 1 (rows 16..31)
    float mm0 = (a0 > 0.f) ? a0 * kmax : a0 * kmin;
    float mm1 = (a1 > 0.f) ? a1 * kmax : a1 * kmin;

    // ---- phase 1: running row-sums for both tiles (no arrays) ----
    float rs0 = 0.f, rs1 = 0.f;
    #pragma unroll
    for (int s = 0; s < 8; s++) {
        const float4* kp = (const float4*)(kml + w * 256 + s * 32 + kg * 8);
        float4 ka = kp[0], kb = kp[1];
        rs0 += __expf(a0 * ka.x - mm0); rs1 += __expf(a1 * ka.x - mm1);
        rs0 += __expf(a0 * ka.y - mm0); rs1 += __expf(a1 * ka.y - mm1);
        rs0 += __expf(a0 * ka.z - mm0); rs1 += __expf(a1 * ka.z - mm1);
        rs0 += __expf(a0 * ka.w - mm0); rs1 += __expf(a1 * ka.w - mm1);
        rs0 += __expf(a0 * kb.x - mm0); rs1 += __expf(a1 * kb.x - mm1);
        rs0 += __expf(a0 * kb.y - mm0); rs1 += __expf(a1 * kb.y - mm1);
        rs0 += __expf(a0 * kb.z - mm0); rs1 += __expf(a1 * kb.z - mm1);
        rs0 += __expf(a0 * kb.w - mm0); rs1 += __expf(a1 * kb.w - mm1);
    }
    rs0 += __shfl_xor(rs0, 16); rs0 += __shfl_xor(rs0, 32);
    rs1 += __shfl_xor(rs1, 16); rs1 += __shfl_xor(rs1, 32);
    if (lane < 16) { wsum0[w][lane] = rs0; wsum1[w][lane] = rs1; }
    __syncthreads();
    float rr0 = 1.f / (wsum0[0][m16] + wsum0[1][m16] + wsum0[2][m16] + wsum0[3][m16]);
    float rr1 = 1.f / (wsum1[0][m16] + wsum1[1][m16] + wsum1[2][m16] + wsum1[3][m16]);

    // ---- phase 2: per s-step, B-fragments loaded once feed BOTH tiles ----
    float* attn_row0 = out + 4194304 + ((size_t)(bh * SL + qt2 * 32 + m16)) * SL;
    float* attn_row1 = attn_row0 + (size_t)16 * SL;
    const short8* vt8 = (const short8*)((const unsigned short*)(ws + VT_OFF))
                        + (size_t)bh * 8192 + w * 2048;

    f32x4 p0a = {0,0,0,0}, p0b = {0,0,0,0}, p0c = {0,0,0,0}, p0d = {0,0,0,0};
    f32x4 p1a = {0,0,0,0}, p1b = {0,0,0,0}, p1c = {0,0,0,0}, p1d = {0,0,0,0};

    #pragma unroll
    for (int s = 0; s < 8; s++) {
        int k0 = w * 256 + s * 32 + kg * 8;
        const float4* kp = (const float4*)(kml + k0);
        float4 ka = kp[0], kb = kp[1];
        const short8* bbase = vt8 + s * 64 + lane;
        short8 b0 = bbase[0 * 512];
        short8 b1 = bbase[1 * 512];
        short8 b2 = bbase[2 * 512];
        short8 b3 = bbase[3 * 512];
        // tile 0
        {
            float es[8];
            es[0] = __expf(a0 * ka.x - mm0) * rr0;
            es[1] = __expf(a0 * ka.y - mm0) * rr0;
            es[2] = __expf(a0 * ka.z - mm0) * rr0;
            es[3] = __expf(a0 * ka.w - mm0) * rr0;
            es[4] = __expf(a0 * kb.x - mm0) * rr0;
            es[5] = __expf(a0 * kb.y - mm0) * rr0;
            es[6] = __expf(a0 * kb.z - mm0) * rr0;
            es[7] = __expf(a0 * kb.w - mm0) * rr0;
            f32x4 v0 = {es[0], es[1], es[2], es[3]};
            f32x4 v1 = {es[4], es[5], es[6], es[7]};
            __builtin_nontemporal_store(v0, (f32x4*)(attn_row0 + k0));
            __builtin_nontemporal_store(v1, (f32x4*)(attn_row0 + k0 + 4));
            unsigned short af[8];
            #pragma unroll
            for (int j = 0; j < 8; j++) af[j] = f2bf(es[j]);
            short8 av = *(short8*)af;
            p0a = __builtin_amdgcn_mfma_f32_16x16x32_bf16(av, b0, p0a, 0, 0, 0);
            p0b = __builtin_amdgcn_mfma_f32_16x16x32_bf16(av, b1, p0b, 0, 0, 0);
            p0c = __builtin_amdgcn_mfma_f32_16x16x32_bf16(av, b2, p0c, 0, 0, 0);
            p0d = __builtin_amdgcn_mfma_f32_16x16x32_bf16(av, b3, p0d, 0, 0, 0);
        }
        // tile 1
        {
            float es[8];
            es[0] = __expf(a1 * ka.x - mm1) * rr1;
            es[1] = __expf(a1 * ka.y - mm1) * rr1;
            es[2] = __expf(a1 * ka.z - mm1) * rr1;
            es[3] = __expf(a1 * ka.w - mm1) * rr1;
            es[4] = __expf(a1 * kb.x - mm1) * rr1;
            es[5] = __expf(a1 * kb.y - mm1) * rr1;
            es[6] = __expf(a1 * kb.z - mm1) * rr1;
            es[7] = __expf(a1 * kb.w - mm1) * rr1;
            f32x4 v0 = {es[0], es[1], es[2], es[3]};
            f32x4 v1 = {es[4], es[5], es[6], es[7]};
            __builtin_nontemporal_store(v0, (f32x4*)(attn_row1 + k0));
            __builtin_nontemporal_store(v1, (f32x4*)(attn_row1 + k0 + 4));
            unsigned short af[8];
            #pragma unroll
            for (int j = 0; j < 8; j++) af[j] = f2bf(es[j]);
            short8 av = *(short8*)af;
            p1a = __builtin_amdgcn_mfma_f32_16x16x32_bf16(av, b0, p1a, 0, 0, 0);
            p1b = __builtin_amdgcn_mfma_f32_16x16x32_bf16(av, b1, p1b, 0, 0, 0);
            p1c = __builtin_amdgcn_mfma_f32_16x16x32_bf16(av, b2, p1c, 0, 0, 0);
            p1d = __builtin_amdgcn_mfma_f32_16x16x32_bf16(av, b3, p1d, 0, 0, 0);
        }
    }

    // ---- cross-wave accumulator reduction, tile 0 then tile 1 ----
    #pragma unroll
    for (int reg = 0; reg < 4; reg++) {
        int r = kg * 4 + reg;
        accred[w][r][ 0 + m16] = p0a[reg];
        accred[w][r][16 + m16] = p0b[reg];
        accred[w][r][32 + m16] = p0c[reg];
        accred[w][r][48 + m16] = p0d[reg];
    }
    __syncthreads();
    {
        int r  = tid >> 4;            // 0..15
        int d0 = (tid & 15) * 4;      // 0..60
        float4 s0 = *(const float4*)&accred[0][r][d0];
        float4 s1 = *(const float4*)&accred[1][r][d0];
        float4 s2 = *(const float4*)&accred[2][r][d0];
        float4 s3 = *(const float4*)&accred[3][r][d0];
        float4 o = make_float4(s0.x + s1.x + s2.x + s3.x,
                               s0.y + s1.y + s2.y + s3.y,
                               s0.z + s1.z + s2.z + s3.z,
                               s0.w + s1.w + s2.w + s3.w);
        float* ctx = out + ((size_t)(bh * SL + qt2 * 32 + r)) * 64 + d0;
        *(float4*)ctx = o;
    }
    __syncthreads();
    #pragma unroll
    for (int reg = 0; reg < 4; reg++) {
        int r = kg * 4 + reg;
        accred[w][r][ 0 + m16] = p1a[reg];
        accred[w][r][16 + m16] = p1b[reg];
        accred[w][r][32 + m16] = p1c[reg];
        accred[w][r][48 + m16] = p1d[reg];
    }
    __syncthreads();
    {
        int r  = tid >> 4;
        int d0 = (tid & 15) * 4;
        float4 s0 = *(const float4*)&accred[0][r][d0];
        float4 s1 = *(const float4*)&accred[1][r][d0];
        float4 s2 = *(const float4*)&accred[2][r][d0];
        float4 s3 = *(const float4*)&accred[3][r][d0];
        float4 o = make_float4(s0.x + s1.x + s2.x + s3.x,
                               s0.y + s1.y + s2.y + s3.y,
                               s0.z + s1.z + s2.z + s3.z,
                               s0.w + s1.w + s2.w + s3.w);
        float* ctx = out + ((size_t)(bh * SL + qt2 * 32 + 16 + r)) * 64 + d0;
        *(float4*)ctx = o;
    }
}

extern "C" void kernel_launch(void* const* d_in, const int* in_sizes, int n_in,
                              void* d_out, int out_size, void* d_ws, size_t ws_size,
                              hipStream_t stream)
{
    const float* Q      = (const float*)d_in[0];
    const float* K      = (const float*)d_in[1];
    const float* V      = (const float*)d_in[2];
    const float* wq     = (const float*)d_in[4];
    const float* wk     = (const float*)d_in[5];
    const float* wbq    = (const float*)d_in[6];
    const float* wbk    = (const float*)d_in[7];
    const float* cq3_w  = (const float*)d_in[8];
    const float* cq3_b  = (const float*)d_in[9];
    const float* cq9_w  = (const float*)d_in[10];
    const float* cq9_b  = (const float*)d_in[11];
    const float* ck3_w  = (const float*)d_in[12];
    const float* ck3_b  = (const float*)d_in[13];
    const float* ck9_w  = (const float*)d_in[14];
    const float* ck9_b  = (const float*)d_in[15];
    const float* bnq3_g = (const float*)d_in[16];
    const float* bnq3_b = (const float*)d_in[17];
    const float* bnq9_g = (const float*)d_in[18];
    const float* bnq9_b = (const float*)d_in[19];
    const float* bnk3_g = (const float*)d_in[20];
    const float* bnk3_b = (const float*)d_in[21];
    const float* bnk9_g = (const float*)d_in[22];
    const float* bnk9_b = (const float*)d_in[23];
    float* out = (float*)d_out;
    float* ws  = (float*)d_ws;

    k_projpack<<<10241, 256, 0, stream>>>(Q, K, V, wq, wk, wbq, wbk, ws);
    k_conv<<<256, 256, 0, stream>>>(ws, cq3_w, cq3_b, cq9_w, cq9_b,
                                    ck3_w, ck3_b, ck9_w, ck9_b);
    k_bnmix<<<128, 256, 0, stream>>>(ws, bnq3_g, bnq3_b, bnq9_g, bnq9_b,
                                     bnk3_g, bnk3_b, bnk9_g, bnk9_b);
    k_attn<<<2048, 256, 0, stream>>>(out, ws);
}

// Round 13
// 399.932 us; speedup vs baseline: 1.1058x; 1.1058x over previous
//
#include <hip/hip_runtime.h>

// Problem constants: B=8, H=8, L=1024, DK=64
constexpr int SL = 1024;   // sequence length
constexpr int NBH = 64;    // B*H rows

// Workspace layout (float offsets)
constexpr int QP_OFF = 0;         // Qp [64][1024]
constexpr int KP_OFF = 65536;     // Kp [64][1024]
constexpr int Y_OFF  = 131072;    // conv outputs, 4 branches x [64][1024]
constexpr int QM_OFF = 655360;    // Qm [64][1024]
constexpr int KM_OFF = 720896;    // Km [64][1024]
constexpr int ST_OFF = 786432;    // BN stats [4][8][2] = 64 floats (atomic accum)
constexpr int C_OFF  = 786496;    // scalar c = dot(wbq,wbk)/8
constexpr int VT_OFF = 786560;    // V packed bf16 B-fragments: 4.19M ushort = 8.4 MB

typedef __attribute__((ext_vector_type(8))) short short8;
typedef __attribute__((ext_vector_type(4))) float f32x4;

__device__ inline unsigned short f2bf(float x) {
    unsigned int u = __float_as_uint(x);
    unsigned int r = (u + 0x7fff + ((u >> 16) & 1)) >> 16;  // RNE
    return (unsigned short)r;
}

// ---------------- K1: proj (Qp,Kp) + c + V bf16 B-fragment pack, fused ----
__global__ __launch_bounds__(256) void k_projpack(
    const float* __restrict__ Q, const float* __restrict__ K,
    const float* __restrict__ V,
    const float* __restrict__ wq, const float* __restrict__ wk,
    const float* __restrict__ wbq, const float* __restrict__ wbk,
    float* __restrict__ ws)
{
    int b = blockIdx.x;
    int tid = threadIdx.x;
    if (b < 8192) {
        bool isQ = b < 4096;
        const float* src = isQ ? Q : K;
        const float* w   = isQ ? wq : wk;
        int row = (b - (isQ ? 0 : 4096)) * 16 + (tid >> 4);
        int l16 = tid & 15;
        float4 x  = ((const float4*)(src + row * 64))[l16];
        float4 w4 = ((const float4*)w)[l16];
        float v = x.x * w4.x + x.y * w4.y + x.z * w4.z + x.w * w4.w;
        #pragma unroll
        for (int m = 8; m; m >>= 1) v += __shfl_xor(v, m);
        if (l16 == 0) ws[(isQ ? QP_OFF : KP_OFF) + row] = v;
    } else if (b < 10240) {
        // V pack: [bh][chunk4][dsub4][kstep8][lane64][j8]
        int t = (b - 8192) * 256 + tid;    // 524288 total
        int lane = t & 63;
        int s    = (t >> 6) & 7;
        int dsub = (t >> 9) & 3;
        int chunk= (t >> 11) & 3;
        int bh   = t >> 13;
        const float* vb = V + bh * (SL * 64);
        int k0 = chunk * 256 + s * 32 + (lane >> 4) * 8;
        int d  = dsub * 16 + (lane & 15);
        unsigned short o[8];
        #pragma unroll
        for (int j = 0; j < 8; j++) o[j] = f2bf(vb[(k0 + j) * 64 + d]);
        unsigned short* vt = (unsigned short*)(ws + VT_OFF);
        *(short8*)(vt + (size_t)t * 8) = *(short8*)o;
    } else {
        if (tid < 64) {
            ws[ST_OFF + tid] = 0.f;        // zero BN-stat accumulators
            float v = wbq[tid] * wbk[tid];
            #pragma unroll
            for (int m = 32; m; m >>= 1) v += __shfl_xor(v, m);
            if (tid == 0) ws[C_OFF] = v * 0.125f;  // / sqrt(64)
        }
    }
}

// ---------------- K2: conv1d + bias, accumulate BN stats ----------------
__global__ __launch_bounds__(256) void k_conv(
    float* __restrict__ ws,
    const float* __restrict__ w0, const float* __restrict__ b0,
    const float* __restrict__ w1, const float* __restrict__ b1,
    const float* __restrict__ w2, const float* __restrict__ b2,
    const float* __restrict__ w3, const float* __restrict__ b3)
{
    int branch = blockIdx.x >> 6;
    int n = (blockIdx.x >> 3) & 7;
    int seg = blockIdx.x & 7;
    int t0 = seg * 128;
    const float* wp = branch == 0 ? w0 : branch == 1 ? w1 : branch == 2 ? w2 : w3;
    const float* bp = branch == 0 ? b0 : branch == 1 ? b1 : branch == 2 ? b2 : b3;
    const int F = (branch & 1) ? 9 : 3;
    const int PAD = F >> 1;
    const float* x = ws + ((branch < 2) ? QP_OFF : KP_OFF) + n * 8 * SL;

    __shared__ float xl[8][136];    // 128 + halo 4 each side (offset +4)
    __shared__ float wl[8 * 8 * 9];
    __shared__ float bl[8];
    int tid = threadIdx.x;
    for (int i = tid; i < 8 * 8 * F; i += 256) wl[i] = wp[i];
    if (tid < 8) bl[tid] = bp[tid];
    for (int i = tid; i < 8 * 136; i += 256) {
        int ci = i / 136; int tt = i - ci * 136;
        int ta = t0 + tt - 4;
        xl[ci][tt] = (ta >= 0 && ta < SL) ? x[ci * SL + ta] : 0.f;
    }
    __syncthreads();
    int c = tid >> 5, u = tid & 31;
    float s1 = 0.f, s2 = 0.f;
    float* yout = ws + Y_OFF + branch * (NBH * SL) + (n * 8 + c) * SL + t0;
    #pragma unroll
    for (int q = 0; q < 4; q++) {
        int tl = q * 32 + u;
        float acc = bl[c];
        for (int ci = 0; ci < 8; ci++) {
            const float* xr = &xl[ci][tl + 4 - PAD];
            const float* wr = &wl[(c * 8 + ci) * F];
            for (int f = 0; f < F; f++) acc += wr[f] * xr[f];
        }
        yout[tl] = acc;
        s1 += acc; s2 += acc * acc;
    }
    #pragma unroll
    for (int m = 16; m; m >>= 1) {
        s1 += __shfl_xor(s1, m);
        s2 += __shfl_xor(s2, m);
    }
    if (u == 0) {
        atomicAdd(&ws[ST_OFF + (branch * 8 + c) * 2],     s1);
        atomicAdd(&ws[ST_OFF + (branch * 8 + c) * 2 + 1], s2);
    }
}

// ---------------- K3: fused BN(train) + softmax + concat-scramble max ------
__global__ __launch_bounds__(256) void k_bnmix(
    float* __restrict__ ws,
    const float* __restrict__ g0, const float* __restrict__ be0,
    const float* __restrict__ g1, const float* __restrict__ be1,
    const float* __restrict__ g2, const float* __restrict__ be2,
    const float* __restrict__ g3, const float* __restrict__ be3)
{
    int blk = blockIdx.x;
    int which = blk >> 6;
    int i = (blk >> 3) & 7, j = blk & 7;
    int n = 2 * i + (j >= 4 ? 1 : 0);
    int br = which * 2 + (n >= 8 ? 1 : 0);
    int row = n & 7;
    int tid = threadIdx.x;
    int half = tid >> 7;               // 0 -> channel c0, 1 -> c0+1
    int u = tid & 127;
    int c = 2 * (j & 3) + half;
    const float* gp = br == 0 ? g0 : br == 1 ? g1 : br == 2 ? g2 : g3;
    const float* bp = br == 0 ? be0 : br == 1 ? be1 : br == 2 ? be2 : be3;
    float s1 = ws[ST_OFF + (br * 8 + c) * 2];
    float s2 = ws[ST_OFF + (br * 8 + c) * 2 + 1];
    float mu  = s1 * (1.f / 8192.f);
    float var = s2 * (1.f / 8192.f) - mu * mu;   // biased var over (B, L)
    float sc = gp[c] * rsqrtf(var + 1e-5f);
    float sh = bp[c] - mu * sc;
    const float* y = ws + Y_OFF + br * (NBH * SL) + (row * 8 + c) * SL;
    float4 ya = ((const float4*)y)[u * 2];
    float4 yb = ((const float4*)y)[u * 2 + 1];
    float z[8] = { ya.x * sc + sh, ya.y * sc + sh, ya.z * sc + sh, ya.w * sc + sh,
                   yb.x * sc + sh, yb.y * sc + sh, yb.z * sc + sh, yb.w * sc + sh };
    float mx = z[0];
    #pragma unroll
    for (int q = 1; q < 8; q++) mx = fmaxf(mx, z[q]);
    __shared__ float r1[4], r2[4];
    #pragma unroll
    for (int m = 32; m; m >>= 1) mx = fmaxf(mx, __shfl_xor(mx, m));
    if ((tid & 63) == 0) r1[tid >> 6] = mx;
    __syncthreads();
    mx = half ? fmaxf(r1[2], r1[3]) : fmaxf(r1[0], r1[1]);
    float e[8];
    float s = 0.f;
    #pragma unroll
    for (int q = 0; q < 8; q++) { e[q] = __expf(z[q] - mx); s += e[q]; }
    #pragma unroll
    for (int m = 32; m; m >>= 1) s += __shfl_xor(s, m);
    if ((tid & 63) == 0) r2[tid >> 6] = s;
    __syncthreads();
    s = half ? (r2[2] + r2[3]) : (r2[0] + r2[1]);
    float inv = 1.f / s;
    float4 o = make_float4(fmaxf(e[0], e[1]) * inv, fmaxf(e[2], e[3]) * inv,
                           fmaxf(e[4], e[5]) * inv, fmaxf(e[6], e[7]) * inv);
    float* outp = ws + (which ? KM_OFF : QM_OFF) + i * 8192 + j * 1024 + half * 512;
    ((float4*)outp)[u] = o;
}

// ---------------- K4: fused rank-1 attn softmax + attn write + MFMA PV ----
// v10: VT sourced from LDS, not L2. 256 blocks = 64 bh x 4 quarters, exactly
// 1 block/CU (no tail). Block stages its bh's FULL 128 KB VT slice + Km in
// LDS once, then runs 8 serial passes of the verified r9 2-tile body with
// B-fragments via ds_read_b128 (pre-session's conflict-free pattern).
// Mechanism (7th theory, only survivor): the 268 MB attn store stream
// transits L2 and continuously evicts VT -> invariant ~220 MB HBM FETCH.
// With VT in LDS, L2 serves only the write stream. LDS: 128 KB dynamic +
// 20.6 KB static = 148.6 KB < 160 KB (gfx950). No launch_bounds cap:
// 1 block/CU anyway, full VGPR budget, zero spill risk.
__global__ void k_attn(
    float* __restrict__ out, const float* __restrict__ ws)
{
    extern __shared__ unsigned short bpk[];   // 128 KB: full bh VT slice
    int p = blockIdx.x;                // 256 blocks
    int xcd = p & 7, j = p >> 3;       // j in 0..31
    int bh = xcd + 8 * (j >> 2);       // 8 bh tables per XCD
    int quarter = j & 3;               // this block: rows quarter*256 .. +255
    int tid = threadIdx.x;

    __shared__ __align__(16) float kml[1024];
    __shared__ float rmx[4], rmn[4];
    __shared__ float wsum0[4][16], wsum1[4][16];
    __shared__ float accred[4][16][64];        // 16 KB, reused per tile

    // ---- stage full VT slice (8192 uint4 = 128 KB), batched for MLP ----
    {
        const uint4* src = (const uint4*)((const unsigned short*)(ws + VT_OFF)
                                          + (size_t)bh * 65536);
        uint4* dst = (uint4*)bpk;
        #pragma unroll
        for (int b = 0; b < 4; ++b) {
            uint4 tmp[8];
            #pragma unroll
            for (int i = 0; i < 8; ++i) tmp[i] = src[tid + 256 * (b * 8 + i)];
            #pragma unroll
            for (int i = 0; i < 8; ++i) dst[tid + 256 * (b * 8 + i)] = tmp[i];
        }
    }

    // ---- stage Km; block max/min (logits monotone in Km -> exact max sub)
    const float* km = ws + KM_OFF + bh * SL;
    float lmax = -1e30f, lmin = 1e30f;
    #pragma unroll
    for (int i = 0; i < 4; i++) {
        float v = km[tid + 256 * i];
        kml[tid + 256 * i] = v;
        lmax = fmaxf(lmax, v); lmin = fminf(lmin, v);
    }
    #pragma unroll
    for (int m = 32; m; m >>= 1) {
        lmax = fmaxf(lmax, __shfl_xor(lmax, m));
        lmin = fminf(lmin, __shfl_xor(lmin, m));
    }
    if ((tid & 63) == 0) { rmx[tid >> 6] = lmax; rmn[tid >> 6] = lmin; }
    __syncthreads();

    int w = tid >> 6, lane = tid & 63;
    int m16 = lane & 15, kg = lane >> 4;
    float kmax = fmaxf(fmaxf(rmx[0], rmx[1]), fmaxf(rmx[2], rmx[3]));
    float kmin = fminf(fminf(rmn[0], rmn[1]), fminf(rmn[2], rmn[3]));
    float c = ws[C_OFF];

    for (int pass = 0; pass < 8; ++pass) {
        int qt2 = quarter * 8 + pass;          // 32-row chunk (2 tiles of 16)
        const float* qm = ws + QM_OFF + bh * SL + qt2 * 32;
        float a0 = c * qm[m16];                // tile 0 (rows 0..15)
        float a1 = c * qm[16 + m16];           // tile 1 (rows 16..31)
        float mm0 = (a0 > 0.f) ? a0 * kmax : a0 * kmin;
        float mm1 = (a1 > 0.f) ? a1 * kmax : a1 * kmin;

        // ---- phase 1: running row-sums for both tiles (no arrays) ----
        float rs0 = 0.f, rs1 = 0.f;
        #pragma unroll
        for (int s = 0; s < 8; s++) {
            const float4* kp = (const float4*)(kml + w * 256 + s * 32 + kg * 8);
            float4 ka = kp[0], kb = kp[1];
            rs0 += __expf(a0 * ka.x - mm0); rs1 += __expf(a1 * ka.x - mm1);
            rs0 += __expf(a0 * ka.y - mm0); rs1 += __expf(a1 * ka.y - mm1);
            rs0 += __expf(a0 * ka.z - mm0); rs1 += __expf(a1 * ka.z - mm1);
            rs0 += __expf(a0 * ka.w - mm0); rs1 += __expf(a1 * ka.w - mm1);
            rs0 += __expf(a0 * kb.x - mm0); rs1 += __expf(a1 * kb.x - mm1);
            rs0 += __expf(a0 * kb.y - mm0); rs1 += __expf(a1 * kb.y - mm1);
            rs0 += __expf(a0 * kb.z - mm0); rs1 += __expf(a1 * kb.z - mm1);
            rs0 += __expf(a0 * kb.w - mm0); rs1 += __expf(a1 * kb.w - mm1);
        }
        rs0 += __shfl_xor(rs0, 16); rs0 += __shfl_xor(rs0, 32);
        rs1 += __shfl_xor(rs1, 16); rs1 += __shfl_xor(rs1, 32);
        if (lane < 16) { wsum0[w][lane] = rs0; wsum1[w][lane] = rs1; }
        __syncthreads();
        float rr0 = 1.f / (wsum0[0][m16] + wsum0[1][m16] + wsum0[2][m16] + wsum0[3][m16]);
        float rr1 = 1.f / (wsum1[0][m16] + wsum1[1][m16] + wsum1[2][m16] + wsum1[3][m16]);

        // ---- phase 2: B-fragments from LDS feed BOTH tiles; store attn ----
        float* attn_row0 = out + 4194304 + ((size_t)(bh * SL + qt2 * 32 + m16)) * SL;
        float* attn_row1 = attn_row0 + (size_t)16 * SL;

        f32x4 p0a = {0,0,0,0}, p0b = {0,0,0,0}, p0c = {0,0,0,0}, p0d = {0,0,0,0};
        f32x4 p1a = {0,0,0,0}, p1b = {0,0,0,0}, p1c = {0,0,0,0}, p1d = {0,0,0,0};

        #pragma unroll
        for (int s = 0; s < 8; s++) {
            int k0 = w * 256 + s * 32 + kg * 8;
            const float4* kp = (const float4*)(kml + k0);
            float4 ka = kp[0], kb = kp[1];
            const short8* bbase = (const short8*)bpk + w * 2048 + s * 64 + lane;
            short8 b0 = bbase[0 * 512];
            short8 b1 = bbase[1 * 512];
            short8 b2 = bbase[2 * 512];
            short8 b3 = bbase[3 * 512];
            // tile 0
            {
                float es[8];
                es[0] = __expf(a0 * ka.x - mm0) * rr0;
                es[1] = __expf(a0 * ka.y - mm0) * rr0;
                es[2] = __expf(a0 * ka.z - mm0) * rr0;
                es[3] = __expf(a0 * ka.w - mm0) * rr0;
                es[4] = __expf(a0 * kb.x - mm0) * rr0;
                es[5] = __expf(a0 * kb.y - mm0) * rr0;
                es[6] = __expf(a0 * kb.z - mm0) * rr0;
                es[7] = __expf(a0 * kb.w - mm0) * rr0;
                *(float4*)(attn_row0 + k0)     = make_float4(es[0], es[1], es[2], es[3]);
                *(float4*)(attn_row0 + k0 + 4) = make_float4(es[4], es[5], es[6], es[7]);
                unsigned short af[8];
                #pragma unroll
                for (int jj = 0; jj < 8; jj++) af[jj] = f2bf(es[jj]);
                short8 av = *(short8*)af;
                p0a = __builtin_amdgcn_mfma_f32_16x16x32_bf16(av, b0, p0a, 0, 0, 0);
                p0b = __builtin_amdgcn_mfma_f32_16x16x32_bf16(av, b1, p0b, 0, 0, 0);
                p0c = __builtin_amdgcn_mfma_f32_16x16x32_bf16(av, b2, p0c, 0, 0, 0);
                p0d = __builtin_amdgcn_mfma_f32_16x16x32_bf16(av, b3, p0d, 0, 0, 0);
            }
            // tile 1
            {
                float es[8];
                es[0] = __expf(a1 * ka.x - mm1) * rr1;
                es[1] = __expf(a1 * ka.y - mm1) * rr1;
                es[2] = __expf(a1 * ka.z - mm1) * rr1;
                es[3] = __expf(a1 * ka.w - mm1) * rr1;
                es[4] = __expf(a1 * kb.x - mm1) * rr1;
                es[5] = __expf(a1 * kb.y - mm1) * rr1;
                es[6] = __expf(a1 * kb.z - mm1) * rr1;
                es[7] = __expf(a1 * kb.w - mm1) * rr1;
                *(float4*)(attn_row1 + k0)     = make_float4(es[0], es[1], es[2], es[3]);
                *(float4*)(attn_row1 + k0 + 4) = make_float4(es[4], es[5], es[6], es[7]);
                unsigned short af[8];
                #pragma unroll
                for (int jj = 0; jj < 8; jj++) af[jj] = f2bf(es[jj]);
                short8 av = *(short8*)af;
                p1a = __builtin_amdgcn_mfma_f32_16x16x32_bf16(av, b0, p1a, 0, 0, 0);
                p1b = __builtin_amdgcn_mfma_f32_16x16x32_bf16(av, b1, p1b, 0, 0, 0);
                p1c = __builtin_amdgcn_mfma_f32_16x16x32_bf16(av, b2, p1c, 0, 0, 0);
                p1d = __builtin_amdgcn_mfma_f32_16x16x32_bf16(av, b3, p1d, 0, 0, 0);
            }
        }

        // ---- cross-wave accumulator reduction, tile 0 then tile 1 ----
        #pragma unroll
        for (int reg = 0; reg < 4; reg++) {
            int r = kg * 4 + reg;
            accred[w][r][ 0 + m16] = p0a[reg];
            accred[w][r][16 + m16] = p0b[reg];
            accred[w][r][32 + m16] = p0c[reg];
            accred[w][r][48 + m16] = p0d[reg];
        }
        __syncthreads();
        {
            int r  = tid >> 4;            // 0..15
            int d0 = (tid & 15) * 4;      // 0..60
            float4 s0 = *(const float4*)&accred[0][r][d0];
            float4 s1 = *(const float4*)&accred[1][r][d0];
            float4 s2 = *(const float4*)&accred[2][r][d0];
            float4 s3 = *(const float4*)&accred[3][r][d0];
            float4 o = make_float4(s0.x + s1.x + s2.x + s3.x,
                                   s0.y + s1.y + s2.y + s3.y,
                                   s0.z + s1.z + s2.z + s3.z,
                                   s0.w + s1.w + s2.w + s3.w);
            float* ctx = out + ((size_t)(bh * SL + qt2 * 32 + r)) * 64 + d0;
            *(float4*)ctx = o;
        }
        __syncthreads();
        #pragma unroll
        for (int reg = 0; reg < 4; reg++) {
            int r = kg * 4 + reg;
            accred[w][r][ 0 + m16] = p1a[reg];
            accred[w][r][16 + m16] = p1b[reg];
            accred[w][r][32 + m16] = p1c[reg];
            accred[w][r][48 + m16] = p1d[reg];
        }
        __syncthreads();
        {
            int r  = tid >> 4;
            int d0 = (tid & 15) * 4;
            float4 s0 = *(const float4*)&accred[0][r][d0];
            float4 s1 = *(const float4*)&accred[1][r][d0];
            float4 s2 = *(const float4*)&accred[2][r][d0];
            float4 s3 = *(const float4*)&accred[3][r][d0];
            float4 o = make_float4(s0.x + s1.x + s2.x + s3.x,
                                   s0.y + s1.y + s2.y + s3.y,
                                   s0.z + s1.z + s2.z + s3.z,
                                   s0.w + s1.w + s2.w + s3.w);
            float* ctx = out + ((size_t)(bh * SL + qt2 * 32 + 16 + r)) * 64 + d0;
            *(float4*)ctx = o;
        }
        __syncthreads();   // protect wsum/accred reuse by next pass
    }
}

extern "C" void kernel_launch(void* const* d_in, const int* in_sizes, int n_in,
                              void* d_out, int out_size, void* d_ws, size_t ws_size,
                              hipStream_t stream)
{
    const float* Q      = (const float*)d_in[0];
    const float* K      = (const float*)d_in[1];
    const float* V      = (const float*)d_in[2];
    const float* wq     = (const float*)d_in[4];
    const float* wk     = (const float*)d_in[5];
    const float* wbq    = (const float*)d_in[6];
    const float* wbk    = (const float*)d_in[7];
    const float* cq3_w  = (const float*)d_in[8];
    const float* cq3_b  = (const float*)d_in[9];
    const float* cq9_w  = (const float*)d_in[10];
    const float* cq9_b  = (const float*)d_in[11];
    const float* ck3_w  = (const float*)d_in[12];
    const float* ck3_b  = (const float*)d_in[13];
    const float* ck9_w  = (const float*)d_in[14];
    const float* ck9_b  = (const float*)d_in[15];
    const float* bnq3_g = (const float*)d_in[16];
    const float* bnq3_b = (const float*)d_in[17];
    const float* bnq9_g = (const float*)d_in[18];
    const float* bnq9_b = (const float*)d_in[19];
    const float* bnk3_g = (const float*)d_in[20];
    const float* bnk3_b = (const float*)d_in[21];
    const float* bnk9_g = (const float*)d_in[22];
    const float* bnk9_b = (const float*)d_in[23];
    float* out = (float*)d_out;
    float* ws  = (float*)d_ws;

    k_projpack<<<10241, 256, 0, stream>>>(Q, K, V, wq, wk, wbq, wbk, ws);
    k_conv<<<256, 256, 0, stream>>>(ws, cq3_w, cq3_b, cq9_w, cq9_b,
                                    ck3_w, ck3_b, ck9_w, ck9_b);
    k_bnmix<<<128, 256, 0, stream>>>(ws, bnq3_g, bnq3_b, bnq9_g, bnq9_b,
                                     bnk3_g, bnk3_b, bnk9_g, bnk9_b);
    k_attn<<<256, 256, 131072, stream>>>(out, ws);
}

// Round 14
// 392.826 us; speedup vs baseline: 1.1258x; 1.0181x over previous
//
#include <hip/hip_runtime.h>

// Problem constants: B=8, H=8, L=1024, DK=64
constexpr int SL = 1024;   // sequence length
constexpr int NBH = 64;    // B*H rows

// Workspace layout (float offsets)
constexpr int QP_OFF = 0;         // Qp [64][1024]
constexpr int KP_OFF = 65536;     // Kp [64][1024]
constexpr int Y_OFF  = 131072;    // conv outputs, 4 branches x [64][1024]
constexpr int QM_OFF = 655360;    // Qm [64][1024]
constexpr int KM_OFF = 720896;    // Km [64][1024]
constexpr int ST_OFF = 786432;    // BN stats [4][8][2] = 64 floats (atomic accum)
constexpr int C_OFF  = 786496;    // scalar c = dot(wbq,wbk)/8
constexpr int VT_OFF = 786560;    // V packed bf16 B-fragments: 4.19M ushort = 8.4 MB

typedef __attribute__((ext_vector_type(8))) short short8;
typedef __attribute__((ext_vector_type(4))) float f32x4;

__device__ inline unsigned short f2bf(float x) {
    unsigned int u = __float_as_uint(x);
    unsigned int r = (u + 0x7fff + ((u >> 16) & 1)) >> 16;  // RNE
    return (unsigned short)r;
}

// ---------------- K1: proj (Qp,Kp) + c + V bf16 B-fragment pack, fused ----
__global__ __launch_bounds__(256) void k_projpack(
    const float* __restrict__ Q, const float* __restrict__ K,
    const float* __restrict__ V,
    const float* __restrict__ wq, const float* __restrict__ wk,
    const float* __restrict__ wbq, const float* __restrict__ wbk,
    float* __restrict__ ws)
{
    int b = blockIdx.x;
    int tid = threadIdx.x;
    if (b < 8192) {
        bool isQ = b < 4096;
        const float* src = isQ ? Q : K;
        const float* w   = isQ ? wq : wk;
        int row = (b - (isQ ? 0 : 4096)) * 16 + (tid >> 4);
        int l16 = tid & 15;
        float4 x  = ((const float4*)(src + row * 64))[l16];
        float4 w4 = ((const float4*)w)[l16];
        float v = x.x * w4.x + x.y * w4.y + x.z * w4.z + x.w * w4.w;
        #pragma unroll
        for (int m = 8; m; m >>= 1) v += __shfl_xor(v, m);
        if (l16 == 0) ws[(isQ ? QP_OFF : KP_OFF) + row] = v;
    } else if (b < 10240) {
        // V pack: [bh][chunk4][dsub4][kstep8][lane64][j8]
        int t = (b - 8192) * 256 + tid;    // 524288 total
        int lane = t & 63;
        int s    = (t >> 6) & 7;
        int dsub = (t >> 9) & 3;
        int chunk= (t >> 11) & 3;
        int bh   = t >> 13;
        const float* vb = V + bh * (SL * 64);
        int k0 = chunk * 256 + s * 32 + (lane >> 4) * 8;
        int d  = dsub * 16 + (lane & 15);
        unsigned short o[8];
        #pragma unroll
        for (int j = 0; j < 8; j++) o[j] = f2bf(vb[(k0 + j) * 64 + d]);
        unsigned short* vt = (unsigned short*)(ws + VT_OFF);
        *(short8*)(vt + (size_t)t * 8) = *(short8*)o;
    } else {
        if (tid < 64) {
            ws[ST_OFF + tid] = 0.f;        // zero BN-stat accumulators
            float v = wbq[tid] * wbk[tid];
            #pragma unroll
            for (int m = 32; m; m >>= 1) v += __shfl_xor(v, m);
            if (tid == 0) ws[C_OFF] = v * 0.125f;  // / sqrt(64)
        }
    }
}

// ---------------- K2: conv1d + bias, accumulate BN stats ----------------
__global__ __launch_bounds__(256) void k_conv(
    float* __restrict__ ws,
    const float* __restrict__ w0, const float* __restrict__ b0,
    const float* __restrict__ w1, const float* __restrict__ b1,
    const float* __restrict__ w2, const float* __restrict__ b2,
    const float* __restrict__ w3, const float* __restrict__ b3)
{
    int branch = blockIdx.x >> 6;
    int n = (blockIdx.x >> 3) & 7;
    int seg = blockIdx.x & 7;
    int t0 = seg * 128;
    const float* wp = branch == 0 ? w0 : branch == 1 ? w1 : branch == 2 ? w2 : w3;
    const float* bp = branch == 0 ? b0 : branch == 1 ? b1 : branch == 2 ? b2 : b3;
    const int F = (branch & 1) ? 9 : 3;
    const int PAD = F >> 1;
    const float* x = ws + ((branch < 2) ? QP_OFF : KP_OFF) + n * 8 * SL;

    __shared__ float xl[8][136];    // 128 + halo 4 each side (offset +4)
    __shared__ float wl[8 * 8 * 9];
    __shared__ float bl[8];
    int tid = threadIdx.x;
    for (int i = tid; i < 8 * 8 * F; i += 256) wl[i] = wp[i];
    if (tid < 8) bl[tid] = bp[tid];
    for (int i = tid; i < 8 * 136; i += 256) {
        int ci = i / 136; int tt = i - ci * 136;
        int ta = t0 + tt - 4;
        xl[ci][tt] = (ta >= 0 && ta < SL) ? x[ci * SL + ta] : 0.f;
    }
    __syncthreads();
    int c = tid >> 5, u = tid & 31;
    float s1 = 0.f, s2 = 0.f;
    float* yout = ws + Y_OFF + branch * (NBH * SL) + (n * 8 + c) * SL + t0;
    #pragma unroll
    for (int q = 0; q < 4; q++) {
        int tl = q * 32 + u;
        float acc = bl[c];
        for (int ci = 0; ci < 8; ci++) {
            const float* xr = &xl[ci][tl + 4 - PAD];
            const float* wr = &wl[(c * 8 + ci) * F];
            for (int f = 0; f < F; f++) acc += wr[f] * xr[f];
        }
        yout[tl] = acc;
        s1 += acc; s2 += acc * acc;
    }
    #pragma unroll
    for (int m = 16; m; m >>= 1) {
        s1 += __shfl_xor(s1, m);
        s2 += __shfl_xor(s2, m);
    }
    if (u == 0) {
        atomicAdd(&ws[ST_OFF + (branch * 8 + c) * 2],     s1);
        atomicAdd(&ws[ST_OFF + (branch * 8 + c) * 2 + 1], s2);
    }
}

// ---------------- K3: fused BN(train) + softmax + concat-scramble max ------
__global__ __launch_bounds__(256) void k_bnmix(
    float* __restrict__ ws,
    const float* __restrict__ g0, const float* __restrict__ be0,
    const float* __restrict__ g1, const float* __restrict__ be1,
    const float* __restrict__ g2, const float* __restrict__ be2,
    const float* __restrict__ g3, const float* __restrict__ be3)
{
    int blk = blockIdx.x;
    int which = blk >> 6;
    int i = (blk >> 3) & 7, j = blk & 7;
    int n = 2 * i + (j >= 4 ? 1 : 0);
    int br = which * 2 + (n >= 8 ? 1 : 0);
    int row = n & 7;
    int tid = threadIdx.x;
    int half = tid >> 7;               // 0 -> channel c0, 1 -> c0+1
    int u = tid & 127;
    int c = 2 * (j & 3) + half;
    const float* gp = br == 0 ? g0 : br == 1 ? g1 : br == 2 ? g2 : g3;
    const float* bp = br == 0 ? be0 : br == 1 ? be1 : br == 2 ? be2 : be3;
    float s1 = ws[ST_OFF + (br * 8 + c) * 2];
    float s2 = ws[ST_OFF + (br * 8 + c) * 2 + 1];
    float mu  = s1 * (1.f / 8192.f);
    float var = s2 * (1.f / 8192.f) - mu * mu;   // biased var over (B, L)
    float sc = gp[c] * rsqrtf(var + 1e-5f);
    float sh = bp[c] - mu * sc;
    const float* y = ws + Y_OFF + br * (NBH * SL) + (row * 8 + c) * SL;
    float4 ya = ((const float4*)y)[u * 2];
    float4 yb = ((const float4*)y)[u * 2 + 1];
    float z[8] = { ya.x * sc + sh, ya.y * sc + sh, ya.z * sc + sh, ya.w * sc + sh,
                   yb.x * sc + sh, yb.y * sc + sh, yb.z * sc + sh, yb.w * sc + sh };
    float mx = z[0];
    #pragma unroll
    for (int q = 1; q < 8; q++) mx = fmaxf(mx, z[q]);
    __shared__ float r1[4], r2[4];
    #pragma unroll
    for (int m = 32; m; m >>= 1) mx = fmaxf(mx, __shfl_xor(mx, m));
    if ((tid & 63) == 0) r1[tid >> 6] = mx;
    __syncthreads();
    mx = half ? fmaxf(r1[2], r1[3]) : fmaxf(r1[0], r1[1]);
    float e[8];
    float s = 0.f;
    #pragma unroll
    for (int q = 0; q < 8; q++) { e[q] = __expf(z[q] - mx); s += e[q]; }
    #pragma unroll
    for (int m = 32; m; m >>= 1) s += __shfl_xor(s, m);
    if ((tid & 63) == 0) r2[tid >> 6] = s;
    __syncthreads();
    s = half ? (r2[2] + r2[3]) : (r2[0] + r2[1]);
    float inv = 1.f / s;
    float4 o = make_float4(fmaxf(e[0], e[1]) * inv, fmaxf(e[2], e[3]) * inv,
                           fmaxf(e[4], e[5]) * inv, fmaxf(e[6], e[7]) * inv);
    float* outp = ws + (which ? KM_OFF : QM_OFF) + i * 8192 + j * 1024 + half * 512;
    ((float4*)outp)[u] = o;
}

// ---------------- K4: fused rank-1 attn softmax + attn write + MFMA PV ----
// FINAL (banked best, r9 = 393.8 us): 2048 blocks = bh(64) x qt2(32 of 32
// rows). Two 16-row tiles per block; per s-step the 4 V B-fragments are
// loaded ONCE and feed both tiles' MFMAs. Verified operating point:
// (256,4), XCD-grouped blocks, single-pass exp via running row-sum +
// per-s-step recompute. Seven k_attn mechanisms tested across r5-r13
// (occupancy, VT traffic, spill, RMW, stream split, NT, LDS-staged VT) —
// all neutral or worse; ~160 us is this output-layout's practical floor
// (268 MB attn across 4 KB-strided row streams sustains ~4.1 TB/s vs the
// 6.2 TB/s single-stream fill ceiling).
__global__ __launch_bounds__(256, 4) void k_attn(
    float* __restrict__ out, const float* __restrict__ ws)
{
    int p = blockIdx.x;
    int xcd = p & 7, idx = p >> 3;            // idx in 0..255
    int bh = xcd + 8 * (idx >> 5);
    int qt2 = idx & 31;                        // 32-row chunk (2 tiles of 16)
    int tid = threadIdx.x;

    __shared__ __align__(16) float kml[1024];
    __shared__ float rmx[4], rmn[4];
    __shared__ float wsum0[4][16], wsum1[4][16];
    __shared__ float accred[4][16][64];        // 16 KB, reused per tile

    const float* km = ws + KM_OFF + bh * SL;
    const float* qm = ws + QM_OFF + bh * SL + qt2 * 32;
    float c = ws[C_OFF];

    // stage Km; block max/min (logits monotone in Km -> exact max subtraction)
    float lmax = -1e30f, lmin = 1e30f;
    #pragma unroll
    for (int i = 0; i < 4; i++) {
        float v = km[tid + 256 * i];
        kml[tid + 256 * i] = v;
        lmax = fmaxf(lmax, v); lmin = fminf(lmin, v);
    }
    #pragma unroll
    for (int m = 32; m; m >>= 1) {
        lmax = fmaxf(lmax, __shfl_xor(lmax, m));
        lmin = fminf(lmin, __shfl_xor(lmin, m));
    }
    if ((tid & 63) == 0) { rmx[tid >> 6] = lmax; rmn[tid >> 6] = lmin; }
    __syncthreads();

    int w = tid >> 6, lane = tid & 63;
    int m16 = lane & 15, kg = lane >> 4;
    float kmax = fmaxf(fmaxf(rmx[0], rmx[1]), fmaxf(rmx[2], rmx[3]));
    float kmin = fminf(fminf(rmn[0], rmn[1]), fminf(rmn[2], rmn[3]));
    float a0 = c * qm[m16];                    // tile 0 (rows 0..15)
    float a1 = c * qm[16 + m16];               // tile 1 (rows 16..31)
    float mm0 = (a0 > 0.f) ? a0 * kmax : a0 * kmin;
    float mm1 = (a1 > 0.f) ? a1 * kmax : a1 * kmin;

    // ---- phase 1: running row-sums for both tiles (no arrays) ----
    float rs0 = 0.f, rs1 = 0.f;
    #pragma unroll
    for (int s = 0; s < 8; s++) {
        const float4* kp = (const float4*)(kml + w * 256 + s * 32 + kg * 8);
        float4 ka = kp[0], kb = kp[1];
        rs0 += __expf(a0 * ka.x - mm0); rs1 += __expf(a1 * ka.x - mm1);
        rs0 += __expf(a0 * ka.y - mm0); rs1 += __expf(a1 * ka.y - mm1);
        rs0 += __expf(a0 * ka.z - mm0); rs1 += __expf(a1 * ka.z - mm1);
        rs0 += __expf(a0 * ka.w - mm0); rs1 += __expf(a1 * ka.w - mm1);
        rs0 += __expf(a0 * kb.x - mm0); rs1 += __expf(a1 * kb.x - mm1);
        rs0 += __expf(a0 * kb.y - mm0); rs1 += __expf(a1 * kb.y - mm1);
        rs0 += __expf(a0 * kb.z - mm0); rs1 += __expf(a1 * kb.z - mm1);
        rs0 += __expf(a0 * kb.w - mm0); rs1 += __expf(a1 * kb.w - mm1);
    }
    rs0 += __shfl_xor(rs0, 16); rs0 += __shfl_xor(rs0, 32);
    rs1 += __shfl_xor(rs1, 16); rs1 += __shfl_xor(rs1, 32);
    if (lane < 16) { wsum0[w][lane] = rs0; wsum1[w][lane] = rs1; }
    __syncthreads();
    float rr0 = 1.f / (wsum0[0][m16] + wsum0[1][m16] + wsum0[2][m16] + wsum0[3][m16]);
    float rr1 = 1.f / (wsum1[0][m16] + wsum1[1][m16] + wsum1[2][m16] + wsum1[3][m16]);

    // ---- phase 2: per s-step, B-fragments loaded once feed BOTH tiles ----
    float* attn_row0 = out + 4194304 + ((size_t)(bh * SL + qt2 * 32 + m16)) * SL;
    float* attn_row1 = attn_row0 + (size_t)16 * SL;
    const short8* vt8 = (const short8*)((const unsigned short*)(ws + VT_OFF))
                        + (size_t)bh * 8192 + w * 2048;

    f32x4 p0a = {0,0,0,0}, p0b = {0,0,0,0}, p0c = {0,0,0,0}, p0d = {0,0,0,0};
    f32x4 p1a = {0,0,0,0}, p1b = {0,0,0,0}, p1c = {0,0,0,0}, p1d = {0,0,0,0};

    #pragma unroll
    for (int s = 0; s < 8; s++) {
        int k0 = w * 256 + s * 32 + kg * 8;
        const float4* kp = (const float4*)(kml + k0);
        float4 ka = kp[0], kb = kp[1];
        const short8* bbase = vt8 + s * 64 + lane;
        short8 b0 = bbase[0 * 512];
        short8 b1 = bbase[1 * 512];
        short8 b2 = bbase[2 * 512];
        short8 b3 = bbase[3 * 512];
        // tile 0
        {
            float es[8];
            es[0] = __expf(a0 * ka.x - mm0) * rr0;
            es[1] = __expf(a0 * ka.y - mm0) * rr0;
            es[2] = __expf(a0 * ka.z - mm0) * rr0;
            es[3] = __expf(a0 * ka.w - mm0) * rr0;
            es[4] = __expf(a0 * kb.x - mm0) * rr0;
            es[5] = __expf(a0 * kb.y - mm0) * rr0;
            es[6] = __expf(a0 * kb.z - mm0) * rr0;
            es[7] = __expf(a0 * kb.w - mm0) * rr0;
            *(float4*)(attn_row0 + k0)     = make_float4(es[0], es[1], es[2], es[3]);
            *(float4*)(attn_row0 + k0 + 4) = make_float4(es[4], es[5], es[6], es[7]);
            unsigned short af[8];
            #pragma unroll
            for (int j = 0; j < 8; j++) af[j] = f2bf(es[j]);
            short8 av = *(short8*)af;
            p0a = __builtin_amdgcn_mfma_f32_16x16x32_bf16(av, b0, p0a, 0, 0, 0);
            p0b = __builtin_amdgcn_mfma_f32_16x16x32_bf16(av, b1, p0b, 0, 0, 0);
            p0c = __builtin_amdgcn_mfma_f32_16x16x32_bf16(av, b2, p0c, 0, 0, 0);
            p0d = __builtin_amdgcn_mfma_f32_16x16x32_bf16(av, b3, p0d, 0, 0, 0);
        }
        // tile 1
        {
            float es[8];
            es[0] = __expf(a1 * ka.x - mm1) * rr1;
            es[1] = __expf(a1 * ka.y - mm1) * rr1;
            es[2] = __expf(a1 * ka.z - mm1) * rr1;
            es[3] = __expf(a1 * ka.w - mm1) * rr1;
            es[4] = __expf(a1 * kb.x - mm1) * rr1;
            es[5] = __expf(a1 * kb.y - mm1) * rr1;
            es[6] = __expf(a1 * kb.z - mm1) * rr1;
            es[7] = __expf(a1 * kb.w - mm1) * rr1;
            *(float4*)(attn_row1 + k0)     = make_float4(es[0], es[1], es[2], es[3]);
            *(float4*)(attn_row1 + k0 + 4) = make_float4(es[4], es[5], es[6], es[7]);
            unsigned short af[8];
            #pragma unroll
            for (int j = 0; j < 8; j++) af[j] = f2bf(es[j]);
            short8 av = *(short8*)af;
            p1a = __builtin_amdgcn_mfma_f32_16x16x32_bf16(av, b0, p1a, 0, 0, 0);
            p1b = __builtin_amdgcn_mfma_f32_16x16x32_bf16(av, b1, p1b, 0, 0, 0);
            p1c = __builtin_amdgcn_mfma_f32_16x16x32_bf16(av, b2, p1c, 0, 0, 0);
            p1d = __builtin_amdgcn_mfma_f32_16x16x32_bf16(av, b3, p1d, 0, 0, 0);
        }
    }

    // ---- cross-wave accumulator reduction, tile 0 then tile 1 ----
    #pragma unroll
    for (int reg = 0; reg < 4; reg++) {
        int r = kg * 4 + reg;
        accred[w][r][ 0 + m16] = p0a[reg];
        accred[w][r][16 + m16] = p0b[reg];
        accred[w][r][32 + m16] = p0c[reg];
        accred[w][r][48 + m16] = p0d[reg];
    }
    __syncthreads();
    {
        int r  = tid >> 4;            // 0..15
        int d0 = (tid & 15) * 4;      // 0..60
        float4 s0 = *(const float4*)&accred[0][r][d0];
        float4 s1 = *(const float4*)&accred[1][r][d0];
        float4 s2 = *(const float4*)&accred[2][r][d0];
        float4 s3 = *(const float4*)&accred[3][r][d0];
        float4 o = make_float4(s0.x + s1.x + s2.x + s3.x,
                               s0.y + s1.y + s2.y + s3.y,
                               s0.z + s1.z + s2.z + s3.z,
                               s0.w + s1.w + s2.w + s3.w);
        float* ctx = out + ((size_t)(bh * SL + qt2 * 32 + r)) * 64 + d0;
        *(float4*)ctx = o;
    }
    __syncthreads();
    #pragma unroll
    for (int reg = 0; reg < 4; reg++) {
        int r = kg * 4 + reg;
        accred[w][r][ 0 + m16] = p1a[reg];
        accred[w][r][16 + m16] = p1b[reg];
        accred[w][r][32 + m16] = p1c[reg];
        accred[w][r][48 + m16] = p1d[reg];
    }
    __syncthreads();
    {
        int r  = tid >> 4;
        int d0 = (tid & 15) * 4;
        float4 s0 = *(const float4*)&accred[0][r][d0];
        float4 s1 = *(const float4*)&accred[1][r][d0];
        float4 s2 = *(const float4*)&accred[2][r][d0];
        float4 s3 = *(const float4*)&accred[3][r][d0];
        float4 o = make_float4(s0.x + s1.x + s2.x + s3.x,
                               s0.y + s1.y + s2.y + s3.y,
                               s0.z + s1.z + s2.z + s3.z,
                               s0.w + s1.w + s2.w + s3.w);
        float* ctx = out + ((size_t)(bh * SL + qt2 * 32 + 16 + r)) * 64 + d0;
        *(float4*)ctx = o;
    }
}

extern "C" void kernel_launch(void* const* d_in, const int* in_sizes, int n_in,
                              void* d_out, int out_size, void* d_ws, size_t ws_size,
                              hipStream_t stream)
{
    const float* Q      = (const float*)d_in[0];
    const float* K      = (const float*)d_in[1];
    const float* V      = (const float*)d_in[2];
    const float* wq     = (const float*)d_in[4];
    const float* wk     = (const float*)d_in[5];
    const float* wbq    = (const float*)d_in[6];
    const float* wbk    = (const float*)d_in[7];
    const float* cq3_w  = (const float*)d_in[8];
    const float* cq3_b  = (const float*)d_in[9];
    const float* cq9_w  = (const float*)d_in[10];
    const float* cq9_b  = (const float*)d_in[11];
    const float* ck3_w  = (const float*)d_in[12];
    const float* ck3_b  = (const float*)d_in[13];
    const float* ck9_w  = (const float*)d_in[14];
    const float* ck9_b  = (const float*)d_in[15];
    const float* bnq3_g = (const float*)d_in[16];
    const float* bnq3_b = (const float*)d_in[17];
    const float* bnq9_g = (const float*)d_in[18];
    const float* bnq9_b = (const float*)d_in[19];
    const float* bnk3_g = (const float*)d_in[20];
    const float* bnk3_b = (const float*)d_in[21];
    const float* bnk9_g = (const float*)d_in[22];
    const float* bnk9_b = (const float*)d_in[23];
    float* out = (float*)d_out;
    float* ws  = (float*)d_ws;

    k_projpack<<<10241, 256, 0, stream>>>(Q, K, V, wq, wk, wbq, wbk, ws);
    k_conv<<<256, 256, 0, stream>>>(ws, cq3_w, cq3_b, cq9_w, cq9_b,
                                    ck3_w, ck3_b, ck9_w, ck9_b);
    k_bnmix<<<128, 256, 0, stream>>>(ws, bnq3_g, bnq3_b, bnq9_g, bnq9_b,
                                     bnk3_g, bnk3_b, bnk9_g, bnk9_b);
    k_attn<<<2048, 256, 0, stream>>>(out, ws);
}